// Round 3
// baseline (1036.776 us; speedup 1.0000x reference)
//
#include <hip/hip_runtime.h>

// ConnectorAttention on MI355X (gfx950), fp16-MFMA implementation.
// Round 6: GEMM K-tile compute split into 3 barrier-separated phases
//   (Q0=A0xB0 / Q1=A0xB1 / Q2+Q3=A1x{B1,B0}) with next-phase ds_reads
//   issued ahead of current MFMAs, sched_barrier(0) pins at phase edges,
//   setprio(1) around each MFMA cluster (T5, gated on phase structure).
//   Staging ring / vmcnt(8) accounting UNCHANGED from round 4 (proven).
//   Flash: setprio around QK and PV MFMA clusters.
// Round 5: flash K/V double-buffered, counted vmcnt(8) pipeline, LDS 80KB.
// Round 4: GEMM 256x256-tile, 512-thread, 4-deep LDS ring (BK=32, 128 KiB),
//   counted vmcnt(8) + raw s_barrier, XOR-granule swizzle, XCD swizzle.
// Round 3: static-max softmax (|s|<=sqrt(128)), lane-partial denominators.
// Round 2: workspace 178.1 MiB (reused WT buffer, fp16 pre, attnb aliases pre).

#define DIM 3840
#define NHEADS 30
#define HDIM 128
#define SEQ 2048
#define BATCH 2
#define MROWS (BATCH * SEQ)   // 4096

typedef _Float16 h8 __attribute__((ext_vector_type(8)));
typedef _Float16 h4 __attribute__((ext_vector_type(4)));
typedef float f32x4 __attribute__((ext_vector_type(4)));

#define GP(p) ((const __attribute__((address_space(1))) void*)(p))
#define LP(p) ((__attribute__((address_space(3))) void*)(p))

// ---------------- conversion kernels ----------------

__global__ __launch_bounds__(256) void convert_h_kernel(
    const float* __restrict__ in, _Float16* __restrict__ out, int n) {
  int i = (blockIdx.x * 256 + threadIdx.x) * 4;
  if (i + 3 < n) {
    float4 v = *reinterpret_cast<const float4*>(in + i);
    h4 o = {(_Float16)v.x, (_Float16)v.y, (_Float16)v.z, (_Float16)v.w};
    *reinterpret_cast<h4*>(out + i) = o;
  }
}

// W [rows][cols] fp32 -> Wt [cols][rows] fp16
__global__ __launch_bounds__(256) void transpose_convert_kernel(
    const float* __restrict__ W, _Float16* __restrict__ Wt, int rows, int cols) {
  __shared__ float tile[32][33];
  int c0 = blockIdx.x * 32, r0 = blockIdx.y * 32;
  int tc = threadIdx.x & 31, tr = threadIdx.x >> 5;
#pragma unroll
  for (int i = 0; i < 32; i += 8)
    tile[tr + i][tc] = W[(size_t)(r0 + tr + i) * cols + c0 + tc];
  __syncthreads();
#pragma unroll
  for (int i = 0; i < 32; i += 8)
    Wt[(size_t)(c0 + tr + i) * rows + r0 + tc] = (_Float16)tile[tc][tr + i];
}

// pre fp16 [B,S,H,D] -> vT fp16 [B,H,D,S]
__global__ __launch_bounds__(256) void transpose_v_kernel(
    const _Float16* __restrict__ pre, _Float16* __restrict__ vT) {
  __shared__ _Float16 tile[32][33];
  int s0 = blockIdx.x * 32, d0 = blockIdx.y * 32, bh = blockIdx.z;
  int b = bh / NHEADS, h = bh % NHEADS;
  int tc = threadIdx.x & 31, tr = threadIdx.x >> 5;
#pragma unroll
  for (int i = 0; i < 32; i += 8) {
    int s = s0 + tr + i, d = d0 + tc;
    tile[tr + i][tc] = pre[((size_t)(b * SEQ + s)) * DIM + h * HDIM + d];
  }
  __syncthreads();
#pragma unroll
  for (int i = 0; i < 32; i += 8) {
    int d = d0 + tr + i, s = s0 + tc;
    vT[((size_t)bh * HDIM + d) * SEQ + s] = tile[tc][tr + i];
  }
}

// ---------------- GEMM: C[M,N] = A[M,K] * Bt[N,K]^T + bias ----------------
// 256x256 tile, BK=32, 512 threads (8 waves, 2Mx4N), fp16 MFMA 16x16x32.
// 4-buffer LDS ring (4 x 32KB = 128KB), counted vmcnt(8): tiles t+1..t+3
// in flight, one raw s_barrier per K-tile, no drain in the main loop.
// Compute phase-split (T3-lite): 3 phases per tile, next-phase frag reads
// issued before current MFMA cluster, s_barrier+sched_barrier(0) at edges,
// setprio around MFMAs (T5).

#define SWZ(row) (((row) & 3) ^ (((row) >> 2) & 3))

template <typename OutT>
__global__ __launch_bounds__(512, 2) void gemm_bt_kernel(
    const _Float16* __restrict__ A, const _Float16* __restrict__ Bt,
    const float* __restrict__ bias, OutT* __restrict__ C,
    int M, int N, int K) {
  __shared__ __align__(16) _Float16 smem[65536];  // 4 x (A 8192 + B 8192) fp16
  const int t = threadIdx.x;
  const int wave = t >> 6, lane = t & 63, quad = lane >> 4, l16 = lane & 15;

  // XCD-aware swizzle: nwg=240, 240%8==0 -> bijective simple form
  const int nwg = gridDim.x;
  const int cpx = nwg >> 3;
  const int bid = blockIdx.x;
  const int swz = (bid & 7) * cpx + (bid >> 3);
  const int ntx = N >> 8;                     // tiles along N (15)
  const int bm = (swz / ntx) << 8, bn = (swz % ntx) << 8;
  const int wm = (wave >> 2) * 128, wn = (wave & 3) * 64;

  const _Float16* Abase = A + (size_t)bm * K;
  const _Float16* Bbase = Bt + (size_t)bn * K;

  const int NT = K >> 5;                      // K-tiles of 32 (120)
  const int srow = wave * 16 + (lane >> 2);   // staging row, round 0
  const int sg = lane & 3;                    // staging granule (linear)

  f32x4 acc[8][4] = {};

  auto stage = [&](int dtile, int bufi) {
    _Float16* bufA = smem + bufi * 16384;
    _Float16* bufB = bufA + 8192;
    const int k0 = dtile << 5;
#pragma unroll
    for (int L = 0; L < 2; ++L) {
      int row = srow + L * 128;
      int g = sg ^ SWZ(row);
      __builtin_amdgcn_global_load_lds(GP(Abase + (size_t)row * K + k0 + g * 8),
                                       LP(bufA + (L * 8 + wave) * 512), 16, 0, 0);
      __builtin_amdgcn_global_load_lds(GP(Bbase + (size_t)row * K + k0 + g * 8),
                                       LP(bufB + (L * 8 + wave) * 512), 16, 0, 0);
    }
  };

  // prologue: stage tiles 0,1,2 into bufs 0,1,2 (12 loads/thread in flight)
#pragma unroll
  for (int pt = 0; pt < 3; ++pt) stage(pt, pt);

  for (int tt = 0; tt < NT; ++tt) {
    // wait until tile tt landed (tiles tt+1, tt+2 = 8 loads may remain),
    // then barrier. Fused in one asm so nothing crosses in either direction.
    asm volatile("s_waitcnt vmcnt(8)\n\ts_barrier" ::: "memory");

    // stage tile tt+3 into the buffer freed by tile tt-1 (clamped at tail;
    // duplicate stages go to buffers that are never read again)
    int dt = tt + 3;
    if (dt >= NT) dt = NT - 1;
    stage(dt, (tt + 3) & 3);

    const _Float16* bufA = smem + (tt & 3) * 16384;
    const _Float16* bufB = bufA + 8192;
    h8 a0[4], a1[4], b0[2], b1[2];

    // pre-reads for phase 0: A rows 0..63 of wave block, B cols 0..31
#pragma unroll
    for (int mi = 0; mi < 4; ++mi) {
      int row = wm + mi * 16 + l16;
      a0[mi] = *reinterpret_cast<const h8*>(bufA + row * 32 + (quad ^ SWZ(row)) * 8);
    }
#pragma unroll
    for (int ni = 0; ni < 2; ++ni) {
      int row = wn + ni * 16 + l16;
      b0[ni] = *reinterpret_cast<const h8*>(bufB + row * 32 + (quad ^ SWZ(row)) * 8);
    }

    // ---- phase 0: prefetch B1, compute Q0 = A0 x B0 ----
#pragma unroll
    for (int ni = 0; ni < 2; ++ni) {
      int row = wn + 32 + ni * 16 + l16;
      b1[ni] = *reinterpret_cast<const h8*>(bufB + row * 32 + (quad ^ SWZ(row)) * 8);
    }
    __builtin_amdgcn_s_setprio(1);
#pragma unroll
    for (int mi = 0; mi < 4; ++mi)
#pragma unroll
      for (int ni = 0; ni < 2; ++ni)
        acc[mi][ni] = __builtin_amdgcn_mfma_f32_16x16x32_f16(a0[mi], b0[ni], acc[mi][ni], 0, 0, 0);
    __builtin_amdgcn_s_setprio(0);
    __builtin_amdgcn_s_barrier();
    __builtin_amdgcn_sched_barrier(0);

    // ---- phase 1: prefetch A1, compute Q1 = A0 x B1 ----
#pragma unroll
    for (int mi = 0; mi < 4; ++mi) {
      int row = wm + 64 + mi * 16 + l16;
      a1[mi] = *reinterpret_cast<const h8*>(bufA + row * 32 + (quad ^ SWZ(row)) * 8);
    }
    __builtin_amdgcn_s_setprio(1);
#pragma unroll
    for (int mi = 0; mi < 4; ++mi)
#pragma unroll
      for (int ni = 0; ni < 2; ++ni)
        acc[mi][2 + ni] = __builtin_amdgcn_mfma_f32_16x16x32_f16(a0[mi], b1[ni], acc[mi][2 + ni], 0, 0, 0);
    __builtin_amdgcn_s_setprio(0);
    __builtin_amdgcn_s_barrier();
    __builtin_amdgcn_sched_barrier(0);

    // ---- phase 2: compute Q2 = A1 x B1, Q3 = A1 x B0 ----
    __builtin_amdgcn_s_setprio(1);
#pragma unroll
    for (int mi = 0; mi < 4; ++mi)
#pragma unroll
      for (int ni = 0; ni < 2; ++ni)
        acc[4 + mi][2 + ni] = __builtin_amdgcn_mfma_f32_16x16x32_f16(a1[mi], b1[ni], acc[4 + mi][2 + ni], 0, 0, 0);
#pragma unroll
    for (int mi = 0; mi < 4; ++mi)
#pragma unroll
      for (int ni = 0; ni < 2; ++ni)
        acc[4 + mi][ni] = __builtin_amdgcn_mfma_f32_16x16x32_f16(a1[mi], b0[ni], acc[4 + mi][ni], 0, 0, 0);
    __builtin_amdgcn_s_setprio(0);
  }

  // drain the tail stages before LDS goes away with the wave
  asm volatile("s_waitcnt vmcnt(0)" ::: "memory");

#pragma unroll
  for (int ni = 0; ni < 4; ++ni) {
    int col = bn + wn + ni * 16 + l16;
    float bv = bias[col];
#pragma unroll
    for (int mi = 0; mi < 8; ++mi) {
      int row0 = bm + wm + mi * 16 + quad * 4;
#pragma unroll
      for (int r = 0; r < 4; ++r)
        C[(size_t)(row0 + r) * N + col] = (OutT)(acc[mi][ni][r] + bv);
    }
  }
}

// ---------------- RMSNorm (row of 3840, fp16 in) -> fp16 [B,H,S,D] --------

__global__ __launch_bounds__(256) void rmsnorm_qk_kernel(
    const _Float16* __restrict__ pre, const float* __restrict__ g,
    _Float16* __restrict__ out, float extra_scale) {
  int row = blockIdx.x;  // 0..4095
  const _Float16* p = pre + (size_t)row * DIM;
  float vals[15];
  float ss = 0.f;
#pragma unroll
  for (int it = 0; it < 15; ++it) {
    float v = (float)p[threadIdx.x + it * 256];
    vals[it] = v;
    ss += v * v;
  }
#pragma unroll
  for (int off = 32; off > 0; off >>= 1) ss += __shfl_down(ss, off, 64);
  __shared__ float red[4];
  if ((threadIdx.x & 63) == 0) red[threadIdx.x >> 6] = ss;
  __syncthreads();
  float scale = rsqrtf((red[0] + red[1] + red[2] + red[3]) * (1.f / DIM) + 1e-6f) * extra_scale;
  int b = row >> 11, s = row & (SEQ - 1);
#pragma unroll
  for (int it = 0; it < 15; ++it) {
    int i = threadIdx.x + it * 256;
    int h = i >> 7, d = i & 127;
    out[(((size_t)b * NHEADS + h) * SEQ + s) * HDIM + d] = (_Float16)(vals[it] * g[i] * scale);
  }
}

// ---------------- Flash attention (static-max softmax, pipelined) ---------
// grid (S/128, B*H). Q tile 128x128 (frags in regs), K/V tiles of 64 keys.
// LDS 80KB: [0,32KB)  K dbuf: 2 x 64x128 (16-granule swizzle)
//           [32,64KB) V dbuf: 2 x 128x64 (8-granule swizzle)
//           [64,80KB) P 128x64 (8-granule swizzle, wave-exclusive rows)
// Q staged through [0,32KB) before the loop (dead before K staging).
// Pipeline: prologue stages tiles 0,1. Per iter: `vmcnt(8); s_barrier`
// (own tile-t loads landed; barrier makes it cross-wave; tile t+1's 8 loads
// stay in flight), compute, raw s_barrier, stage tile t+2 into vacated buf.
// softmax: p = exp(s - 12), lane-partial denominators in registers.
// setprio(1) wraps both MFMA clusters (T5).

#define KOFF 0
#define VOFF 16384
#define POFF 32768

__global__ __launch_bounds__(256) void flash_attn_kernel(
    const _Float16* __restrict__ q, const _Float16* __restrict__ k,
    const _Float16* __restrict__ vT, _Float16* __restrict__ attnb) {
  __shared__ __align__(16) _Float16 smem[40960];  // 80 KB
  const int t = threadIdx.x, wave = t >> 6, lane = t & 63, quad = lane >> 4, l16 = lane & 15;
  const int qt = blockIdx.x, bh = blockIdx.y, b = bh / NHEADS, h = bh % NHEADS;
  const _Float16* qbase = q + ((size_t)bh * SEQ + qt * 128) * HDIM;
  const _Float16* kbase = k + (size_t)bh * SEQ * HDIM;
  const _Float16* vbase = vT + (size_t)bh * HDIM * SEQ;
  const int wm = wave * 32;

  // stage Q 128x128 (16-granule swizzle) through [0,32KB), pull frags to regs
#pragma unroll
  for (int j = 0; j < 8; ++j) {
    int row = j * 16 + (t >> 4);
    int c = (t & 15) ^ (row & 15);
    __builtin_amdgcn_global_load_lds(GP(qbase + (size_t)row * HDIM + c * 8),
                                     LP(smem + j * 2048 + wave * 512), 16, 0, 0);
  }
  __syncthreads();  // full drain: Q visible to all waves
  h8 qf[2][4];
#pragma unroll
  for (int mt = 0; mt < 2; ++mt)
#pragma unroll
    for (int ks = 0; ks < 4; ++ks) {
      int row = wm + mt * 16 + l16;
      qf[mt][ks] = *reinterpret_cast<const h8*>(
          smem + row * 128 + ((ks * 4 + quad) ^ (row & 15)) * 8);
    }
  __syncthreads();  // all waves own their Q frags before K staging overwrites

  f32x4 oacc[2][8] = {};
  float lst[2][4] = {};  // lane-partial softmax denominators

  auto stageKV = [&](int tile, int bufi) {
    const int kt = tile * 64;
    _Float16* kb_ = smem + KOFF + bufi * 8192;
    _Float16* vb_ = smem + VOFF + bufi * 8192;
    // K tile: 64 keys x 128 d (16-granule swizzle)
#pragma unroll
    for (int j = 0; j < 4; ++j) {
      int row = j * 16 + (t >> 4);
      int c = (t & 15) ^ (row & 15);
      __builtin_amdgcn_global_load_lds(GP(kbase + (size_t)(kt + row) * HDIM + c * 8),
                                       LP(kb_ + j * 2048 + wave * 512), 16, 0, 0);
    }
    // V^T tile: 128 d x 64 s (8-granule swizzle)
#pragma unroll
    for (int j = 0; j < 4; ++j) {
      int row = j * 32 + (t >> 3);
      int c = (t & 7) ^ (row & 7);
      __builtin_amdgcn_global_load_lds(GP(vbase + (size_t)row * SEQ + kt + c * 8),
                                       LP(vb_ + j * 2048 + wave * 512), 16, 0, 0);
    }
  };

  // prologue: tiles 0,1 in flight (16 loads/thread)
  stageKV(0, 0);
  stageKV(1, 1);

  for (int tt = 0; tt < SEQ / 64; ++tt) {
    // own tile-tt loads landed (tile tt+1's 8 may remain), then barrier:
    // every wave pre-waited its own slice -> whole tile visible after barrier.
    asm volatile("s_waitcnt vmcnt(8)\n\ts_barrier" ::: "memory");

    const _Float16* kls = smem + KOFF + (tt & 1) * 8192;
    const _Float16* vls = smem + VOFF + (tt & 1) * 8192;

    // S = Q K^T (1/sqrt(d) pre-folded into q)
    f32x4 sacc[2][4] = {};
    __builtin_amdgcn_s_setprio(1);
#pragma unroll
    for (int ks = 0; ks < 4; ++ks)
#pragma unroll
      for (int nt = 0; nt < 4; ++nt) {
        int rowB = nt * 16 + l16;
        h8 kf = *reinterpret_cast<const h8*>(
            kls + rowB * 128 + ((ks * 4 + quad) ^ (rowB & 15)) * 8);
#pragma unroll
        for (int mt = 0; mt < 2; ++mt)
          sacc[mt][nt] = __builtin_amdgcn_mfma_f32_16x16x32_f16(qf[mt][ks], kf, sacc[mt][nt], 0, 0, 0);
      }
    __builtin_amdgcn_s_setprio(0);

    // p = exp(s - 12): write P to wave-exclusive LDS rows, accumulate
    // lane-partial denominators. No shuffles, no rescale, no barrier.
#pragma unroll
    for (int mt = 0; mt < 2; ++mt)
#pragma unroll
      for (int nt = 0; nt < 4; ++nt) {
        int colg = nt * 2 + (l16 >> 3);
        int ce = l16 & 7;
#pragma unroll
        for (int r = 0; r < 4; ++r) {
          float e = __expf(sacc[mt][nt][r] - 12.0f);
          lst[mt][r] += e;
          int row = wm + mt * 16 + quad * 4 + r;
          smem[POFF + row * 64 + ((colg ^ (row & 7)) * 8) + ce] = (_Float16)e;
        }
      }

    // O += P V  (P rows are wave-exclusive; intra-wave lgkmcnt orders it)
    __builtin_amdgcn_s_setprio(1);
#pragma unroll
    for (int ks = 0; ks < 2; ++ks) {
      h8 pf[2];
#pragma unroll
      for (int mt = 0; mt < 2; ++mt) {
        int row = wm + mt * 16 + l16;
        pf[mt] = *reinterpret_cast<const h8*>(
            smem + POFF + row * 64 + ((ks * 4 + quad) ^ (row & 7)) * 8);
      }
#pragma unroll
      for (int nt = 0; nt < 8; ++nt) {
        int rowV = nt * 16 + l16;
        h8 vf = *reinterpret_cast<const h8*>(
            vls + rowV * 64 + ((ks * 4 + quad) ^ (rowV & 7)) * 8);
#pragma unroll
        for (int mt = 0; mt < 2; ++mt)
          oacc[mt][nt] = __builtin_amdgcn_mfma_f32_16x16x32_f16(pf[mt], vf, oacc[mt][nt], 0, 0, 0);
      }
    }
    __builtin_amdgcn_s_setprio(0);

    // all waves done reading K/V[tt&1] -> safe to overwrite with tile tt+2.
    // No drain: tile tt+1's loads stay in flight across this barrier.
    asm volatile("s_barrier" ::: "memory");
    int dt = tt + 2;
    if (dt >= SEQ / 64) dt = SEQ / 64 - 1;  // clamp keeps vmcnt uniform
    stageKV(dt, tt & 1);
  }
  asm volatile("s_waitcnt vmcnt(0)" ::: "memory");  // drain tail stages

  // epilogue: reduce lane-partial denominators across l16, normalize, write
#pragma unroll
  for (int mt = 0; mt < 2; ++mt)
#pragma unroll
    for (int r = 0; r < 4; ++r) {
      float s = lst[mt][r];
#pragma unroll
      for (int off = 1; off <= 8; off <<= 1) s += __shfl_xor(s, off, 64);
      float inv = 1.f / s;
      int srow = qt * 128 + wm + mt * 16 + quad * 4 + r;
#pragma unroll
      for (int nt = 0; nt < 8; ++nt) {
        int d = nt * 16 + l16;
        attnb[((size_t)(b * SEQ + srow)) * DIM + h * HDIM + d] = (_Float16)(oacc[mt][nt][r] * inv);
      }
    }
}

// ---------------- launch ----------------

extern "C" void kernel_launch(void* const* d_in, const int* in_sizes, int n_in,
                              void* d_out, int out_size, void* d_ws, size_t ws_size,
                              hipStream_t stream) {
  const float* x  = (const float*)d_in[0];
  const float* Wq = (const float*)d_in[1];
  const float* bq = (const float*)d_in[2];
  const float* Wk = (const float*)d_in[3];
  const float* bk = (const float*)d_in[4];
  const float* Wv = (const float*)d_in[5];
  const float* bv = (const float*)d_in[6];
  const float* Wo = (const float*)d_in[7];
  const float* bo = (const float*)d_in[8];
  const float* gq = (const float*)d_in[9];
  const float* gk = (const float*)d_in[10];
  float* out = (float*)d_out;

  // workspace layout (total 186,777,600 B = 178.1 MiB)
  char* ws = (char*)d_ws;
  _Float16* xb    = (_Float16*)(ws);                 //  31,457,280 B
  _Float16* WT    = (_Float16*)(ws +  31457280LL);   //  29,491,200 B (reused x4)
  _Float16* qb    = (_Float16*)(ws +  60948480LL);   //  31,457,280 B
  _Float16* kb    = (_Float16*)(ws +  92405760LL);   //  31,457,280 B
  _Float16* vT    = (_Float16*)(ws + 123863040LL);   //  31,457,280 B
  _Float16* pre16 = (_Float16*)(ws + 155320320LL);   //  31,457,280 B
  _Float16* attnb = pre16;  // pre16 dead before flash writes attnb

  convert_h_kernel<<<15360, 256, 0, stream>>>(x, xb, MROWS * DIM);
  dim3 tgrid(DIM / 32, DIM / 32);
  const int ggrid = (DIM / 256) * (MROWS / 256);  // 15 * 16 = 240 blocks

  // Q
  transpose_convert_kernel<<<tgrid, 256, 0, stream>>>(Wq, WT, DIM, DIM);
  gemm_bt_kernel<_Float16><<<ggrid, 512, 0, stream>>>(xb, WT, bq, pre16, MROWS, DIM, DIM);
  rmsnorm_qk_kernel<<<MROWS, 256, 0, stream>>>(pre16, gq, qb, 0.08838834764831845f);  // 1/sqrt(128)
  // K
  transpose_convert_kernel<<<tgrid, 256, 0, stream>>>(Wk, WT, DIM, DIM);
  gemm_bt_kernel<_Float16><<<ggrid, 512, 0, stream>>>(xb, WT, bk, pre16, MROWS, DIM, DIM);
  rmsnorm_qk_kernel<<<MROWS, 256, 0, stream>>>(pre16, gk, kb, 1.0f);
  // V
  transpose_convert_kernel<<<tgrid, 256, 0, stream>>>(Wv, WT, DIM, DIM);
  gemm_bt_kernel<_Float16><<<ggrid, 512, 0, stream>>>(xb, WT, bv, pre16, MROWS, DIM, DIM);
  dim3 vgrid(SEQ / 32, HDIM / 32, BATCH * NHEADS);
  transpose_v_kernel<<<vgrid, 256, 0, stream>>>(pre16, vT);

  // attention
  dim3 agrid(SEQ / 128, BATCH * NHEADS);  // (16, 60)
  flash_attn_kernel<<<agrid, 256, 0, stream>>>(qb, kb, vT, attnb);

  // output projection
  transpose_convert_kernel<<<tgrid, 256, 0, stream>>>(Wo, WT, DIM, DIM);
  gemm_bt_kernel<float><<<ggrid, 512, 0, stream>>>(attnb, WT, bo, out, MROWS, DIM, DIM);
}

// Round 4
// 981.575 us; speedup vs baseline: 1.0562x; 1.0562x over previous
//
#include <hip/hip_runtime.h>

// ConnectorAttention on MI355X (gfx950), fp16-MFMA implementation.
// Round 7: GEMM rebuilt on the m201 8-phase template: BK=64, 2-deep dbuf
//   (128 KiB), 4 phases per K-tile, each {ds_read 4-8 frags || stage one
//   half-tile -> s_barrier -> lgkmcnt(0)+sched_barrier -> setprio(1) ->
//   16 MFMA -> setprio(0) -> s_barrier}. B(t+2) stages into the compute
//   buffer at phase 4 (B region dead after phase 3). One fused
//   `s_waitcnt vmcnt(4); s_barrier` per K-tile -- loads never drained.
//   Flash reverted to round-5 exact (round-6 setprio there cost 4%).
// Round 5: flash K/V double-buffered, counted vmcnt(8) pipeline, LDS 80KB.
// Round 4: counted-vmcnt staging ring + XOR-granule swizzle + XCD swizzle.
// Round 3: static-max softmax (|s|<=sqrt(128)), lane-partial denominators.
// Round 2: workspace 178.1 MiB (reused WT buffer, fp16 pre, attnb aliases pre).

#define DIM 3840
#define NHEADS 30
#define HDIM 128
#define SEQ 2048
#define BATCH 2
#define MROWS (BATCH * SEQ)   // 4096

typedef _Float16 h8 __attribute__((ext_vector_type(8)));
typedef _Float16 h4 __attribute__((ext_vector_type(4)));
typedef float f32x4 __attribute__((ext_vector_type(4)));

#define GP(p) ((const __attribute__((address_space(1))) void*)(p))
#define LP(p) ((__attribute__((address_space(3))) void*)(p))

// ---------------- conversion kernels ----------------

__global__ __launch_bounds__(256) void convert_h_kernel(
    const float* __restrict__ in, _Float16* __restrict__ out, int n) {
  int i = (blockIdx.x * 256 + threadIdx.x) * 4;
  if (i + 3 < n) {
    float4 v = *reinterpret_cast<const float4*>(in + i);
    h4 o = {(_Float16)v.x, (_Float16)v.y, (_Float16)v.z, (_Float16)v.w};
    *reinterpret_cast<h4*>(out + i) = o;
  }
}

// W [rows][cols] fp32 -> Wt [cols][rows] fp16
__global__ __launch_bounds__(256) void transpose_convert_kernel(
    const float* __restrict__ W, _Float16* __restrict__ Wt, int rows, int cols) {
  __shared__ float tile[32][33];
  int c0 = blockIdx.x * 32, r0 = blockIdx.y * 32;
  int tc = threadIdx.x & 31, tr = threadIdx.x >> 5;
#pragma unroll
  for (int i = 0; i < 32; i += 8)
    tile[tr + i][tc] = W[(size_t)(r0 + tr + i) * cols + c0 + tc];
  __syncthreads();
#pragma unroll
  for (int i = 0; i < 32; i += 8)
    Wt[(size_t)(c0 + tr + i) * rows + r0 + tc] = (_Float16)tile[tc][tr + i];
}

// pre fp16 [B,S,H,D] -> vT fp16 [B,H,D,S]
__global__ __launch_bounds__(256) void transpose_v_kernel(
    const _Float16* __restrict__ pre, _Float16* __restrict__ vT) {
  __shared__ _Float16 tile[32][33];
  int s0 = blockIdx.x * 32, d0 = blockIdx.y * 32, bh = blockIdx.z;
  int b = bh / NHEADS, h = bh % NHEADS;
  int tc = threadIdx.x & 31, tr = threadIdx.x >> 5;
#pragma unroll
  for (int i = 0; i < 32; i += 8) {
    int s = s0 + tr + i, d = d0 + tc;
    tile[tr + i][tc] = pre[((size_t)(b * SEQ + s)) * DIM + h * HDIM + d];
  }
  __syncthreads();
#pragma unroll
  for (int i = 0; i < 32; i += 8) {
    int d = d0 + tr + i, s = s0 + tc;
    vT[((size_t)bh * HDIM + d) * SEQ + s] = tile[tc][tr + i];
  }
}

// ---------------- GEMM: C[M,N] = A[M,K] * Bt[N,K]^T + bias ----------------
// 256x256 tile, BK=64, 512 threads (8 waves, 2Mx4N), fp16 MFMA 16x16x32.
// LDS 128KB: 2 dbufs x (A 256x64 + B 256x64). 4 phases per K-tile:
//   ph1: read bf[ks0](4) + afl[ks0](4); stage A_lo(t+1)->other buf; 16 MFMA
//   ph2: read afh[ks0](4);              stage A_hi(t+1)->other buf; 16 MFMA
//   ph3: read bf[ks1](4) + afl[ks1](4); (no stage);                 16 MFMA
//   ph4: read afh[ks1](4);              stage B(t+2)->THIS buf;     16 MFMA
// B region of the compute buf is dead after ph3's lgkm+barrier, so the ph4
// B-stage into it is safe. Each phase: reads/stage -> s_barrier ->
// lgkmcnt(0)+sched_barrier(0) -> setprio(1) -> MFMA -> setprio(0) ->
// s_barrier. K-tile boundary: fused `s_waitcnt vmcnt(4); s_barrier`
// (A(t+1) landed; B(t+2)'s 4 loads stay in flight -- never drained).
// Rows are 64 halfs (8 x 16B granules); XOR swizzle g ^= (row&7) applied to
// the pre-swizzled GLOBAL source (LDS dest linear) and to ds_read addrs:
// 8 lanes/granule over 128B-strided rows = uniform 8 req/bank = conflict-free.

template <typename OutT>
__global__ __launch_bounds__(512, 2) void gemm_bt_kernel(
    const _Float16* __restrict__ A, const _Float16* __restrict__ Bt,
    const float* __restrict__ bias, OutT* __restrict__ C,
    int M, int N, int K) {
  __shared__ __align__(16) _Float16 smem[65536];  // 2 x (A 16384 + B 16384)
  const int t = threadIdx.x;
  const int wave = t >> 6, lane = t & 63, quad = lane >> 4, l16 = lane & 15;

  // XCD-aware swizzle: nwg=240, 240%8==0 -> bijective simple form
  const int nwg = gridDim.x;
  const int cpx = nwg >> 3;
  const int bid = blockIdx.x;
  const int swz = (bid & 7) * cpx + (bid >> 3);
  const int ntx = N >> 8;                     // tiles along N (15)
  const int bm = (swz / ntx) << 8, bn = (swz % ntx) << 8;
  const int wm = (wave >> 2) * 128, wn = (wave & 3) * 64;

  const _Float16* Abase = A + (size_t)bm * K;
  const _Float16* Bbase = Bt + (size_t)bn * K;
  const int NT = K >> 6;                      // K-tiles of 64 (60)

  f32x4 acc[8][4] = {};

  // stage one half (128 rows x 64 halfs = 16KB) of A (isB=0) or B (isB=1)
  // of the K-tile starting at k0, into dbuf d. 2 x global_load_lds / thread.
  auto stage_half = [&](const _Float16* Gb, int d, int isB, int h, int k0) {
    _Float16* Lb = smem + d * 32768 + isB * 16384 + h * 8192;
#pragma unroll
    for (int L = 0; L < 2; ++L) {
      int slot = L * 512 + t;                 // 0..1023
      int row = h * 128 + (slot >> 3);        // tile row 0..255
      int gs = (slot & 7) ^ (row & 7);        // pre-swizzled source granule
      __builtin_amdgcn_global_load_lds(GP(Gb + (size_t)row * K + k0 + gs * 8),
                                       LP(Lb + slot * 8), 16, 0, 0);
    }
  };

  // prologue: B(0), A(0), B(1) -- 12 loads/thread; then tile 0 landed with
  // B(1)'s 4 still in flight (steady-state invariant).
  stage_half(Bbase, 0, 1, 0, 0);  stage_half(Bbase, 0, 1, 1, 0);
  stage_half(Abase, 0, 0, 0, 0);  stage_half(Abase, 0, 0, 1, 0);
  stage_half(Bbase, 1, 1, 0, 64); stage_half(Bbase, 1, 1, 1, 64);
  asm volatile("s_waitcnt vmcnt(4)\n\ts_barrier" ::: "memory");

  for (int tt = 0; tt < NT; ++tt) {
    const _Float16* bufA = smem + (tt & 1) * 32768;
    const _Float16* bufB = bufA + 16384;
    const int dnx = (tt + 1) & 1;
    const int k1 = (tt + 1 < NT ? tt + 1 : NT - 1) << 6;  // A(t+1), clamped
    const int k2 = (tt + 2 < NT ? tt + 2 : NT - 1) << 6;  // B(t+2), clamped
    h8 afl[4], afh[4], bf[4];

    // ---- phase 1: read bf[ks0], afl[ks0]; stage A_lo(t+1); Qlo x ks0 ----
#pragma unroll
    for (int ni = 0; ni < 4; ++ni) {
      int row = wn + ni * 16 + l16;
      bf[ni] = *reinterpret_cast<const h8*>(bufB + row * 64 + (quad ^ (row & 7)) * 8);
    }
#pragma unroll
    for (int mi = 0; mi < 4; ++mi) {
      int row = wm + mi * 16 + l16;
      afl[mi] = *reinterpret_cast<const h8*>(bufA + row * 64 + (quad ^ (row & 7)) * 8);
    }
    stage_half(Abase, dnx, 0, 0, k1);
    __builtin_amdgcn_s_barrier();
    asm volatile("s_waitcnt lgkmcnt(0)" ::: "memory");
    __builtin_amdgcn_sched_barrier(0);
    __builtin_amdgcn_s_setprio(1);
#pragma unroll
    for (int mi = 0; mi < 4; ++mi)
#pragma unroll
      for (int ni = 0; ni < 4; ++ni)
        acc[mi][ni] = __builtin_amdgcn_mfma_f32_16x16x32_f16(afl[mi], bf[ni], acc[mi][ni], 0, 0, 0);
    __builtin_amdgcn_s_setprio(0);
    __builtin_amdgcn_s_barrier();

    // ---- phase 2: read afh[ks0]; stage A_hi(t+1); Qhi x ks0 ----
#pragma unroll
    for (int mi = 0; mi < 4; ++mi) {
      int row = wm + 64 + mi * 16 + l16;
      afh[mi] = *reinterpret_cast<const h8*>(bufA + row * 64 + (quad ^ (row & 7)) * 8);
    }
    stage_half(Abase, dnx, 0, 1, k1);
    __builtin_amdgcn_s_barrier();
    asm volatile("s_waitcnt lgkmcnt(0)" ::: "memory");
    __builtin_amdgcn_sched_barrier(0);
    __builtin_amdgcn_s_setprio(1);
#pragma unroll
    for (int mi = 0; mi < 4; ++mi)
#pragma unroll
      for (int ni = 0; ni < 4; ++ni)
        acc[4 + mi][ni] = __builtin_amdgcn_mfma_f32_16x16x32_f16(afh[mi], bf[ni], acc[4 + mi][ni], 0, 0, 0);
    __builtin_amdgcn_s_setprio(0);
    __builtin_amdgcn_s_barrier();

    // ---- phase 3: read bf[ks1], afl[ks1]; no stage; Qlo x ks1 ----
#pragma unroll
    for (int ni = 0; ni < 4; ++ni) {
      int row = wn + ni * 16 + l16;
      bf[ni] = *reinterpret_cast<const h8*>(bufB + row * 64 + ((4 + quad) ^ (row & 7)) * 8);
    }
#pragma unroll
    for (int mi = 0; mi < 4; ++mi) {
      int row = wm + mi * 16 + l16;
      afl[mi] = *reinterpret_cast<const h8*>(bufA + row * 64 + ((4 + quad) ^ (row & 7)) * 8);
    }
    __builtin_amdgcn_s_barrier();
    asm volatile("s_waitcnt lgkmcnt(0)" ::: "memory");
    __builtin_amdgcn_sched_barrier(0);
    __builtin_amdgcn_s_setprio(1);
#pragma unroll
    for (int mi = 0; mi < 4; ++mi)
#pragma unroll
      for (int ni = 0; ni < 4; ++ni)
        acc[mi][ni] = __builtin_amdgcn_mfma_f32_16x16x32_f16(afl[mi], bf[ni], acc[mi][ni], 0, 0, 0);
    __builtin_amdgcn_s_setprio(0);
    __builtin_amdgcn_s_barrier();

    // ---- phase 4: read afh[ks1]; stage B(t+2) into THIS buf (B dead);
    //      Qhi x ks1; fused vmcnt(4)+barrier = K-tile boundary ----
#pragma unroll
    for (int mi = 0; mi < 4; ++mi) {
      int row = wm + 64 + mi * 16 + l16;
      afh[mi] = *reinterpret_cast<const h8*>(bufA + row * 64 + ((4 + quad) ^ (row & 7)) * 8);
    }
    stage_half(Bbase, tt & 1, 1, 0, k2);
    stage_half(Bbase, tt & 1, 1, 1, k2);
    __builtin_amdgcn_s_barrier();
    asm volatile("s_waitcnt lgkmcnt(0)" ::: "memory");
    __builtin_amdgcn_sched_barrier(0);
    __builtin_amdgcn_s_setprio(1);
#pragma unroll
    for (int mi = 0; mi < 4; ++mi)
#pragma unroll
      for (int ni = 0; ni < 4; ++ni)
        acc[4 + mi][ni] = __builtin_amdgcn_mfma_f32_16x16x32_f16(afh[mi], bf[ni], acc[4 + mi][ni], 0, 0, 0);
    __builtin_amdgcn_s_setprio(0);
    asm volatile("s_waitcnt vmcnt(4)\n\ts_barrier" ::: "memory");
  }

  // drain the tail stages before LDS goes away with the wave
  asm volatile("s_waitcnt vmcnt(0)" ::: "memory");

#pragma unroll
  for (int ni = 0; ni < 4; ++ni) {
    int col = bn + wn + ni * 16 + l16;
    float bv = bias[col];
#pragma unroll
    for (int mi = 0; mi < 8; ++mi) {
      int row0 = bm + wm + mi * 16 + quad * 4;
#pragma unroll
      for (int r = 0; r < 4; ++r)
        C[(size_t)(row0 + r) * N + col] = (OutT)(acc[mi][ni][r] + bv);
    }
  }
}

// ---------------- RMSNorm (row of 3840, fp16 in) -> fp16 [B,H,S,D] --------

__global__ __launch_bounds__(256) void rmsnorm_qk_kernel(
    const _Float16* __restrict__ pre, const float* __restrict__ g,
    _Float16* __restrict__ out, float extra_scale) {
  int row = blockIdx.x;  // 0..4095
  const _Float16* p = pre + (size_t)row * DIM;
  float vals[15];
  float ss = 0.f;
#pragma unroll
  for (int it = 0; it < 15; ++it) {
    float v = (float)p[threadIdx.x + it * 256];
    vals[it] = v;
    ss += v * v;
  }
#pragma unroll
  for (int off = 32; off > 0; off >>= 1) ss += __shfl_down(ss, off, 64);
  __shared__ float red[4];
  if ((threadIdx.x & 63) == 0) red[threadIdx.x >> 6] = ss;
  __syncthreads();
  float scale = rsqrtf((red[0] + red[1] + red[2] + red[3]) * (1.f / DIM) + 1e-6f) * extra_scale;
  int b = row >> 11, s = row & (SEQ - 1);
#pragma unroll
  for (int it = 0; it < 15; ++it) {
    int i = threadIdx.x + it * 256;
    int h = i >> 7, d = i & 127;
    out[(((size_t)b * NHEADS + h) * SEQ + s) * HDIM + d] = (_Float16)(vals[it] * g[i] * scale);
  }
}

// ---------------- Flash attention (static-max softmax, pipelined) ---------
// grid (S/128, B*H). Q tile 128x128 (frags in regs), K/V tiles of 64 keys.
// LDS 80KB: [0,32KB)  K dbuf: 2 x 64x128 (16-granule swizzle)
//           [32,64KB) V dbuf: 2 x 128x64 (8-granule swizzle)
//           [64,80KB) P 128x64 (8-granule swizzle, wave-exclusive rows)
// Q staged through [0,32KB) before the loop (dead before K staging).
// Pipeline: prologue stages tiles 0,1. Per iter: `vmcnt(8); s_barrier`
// (own tile-t loads landed; barrier makes it cross-wave; tile t+1's 8 loads
// stay in flight), compute, raw s_barrier, stage tile t+2 into vacated buf.
// softmax: p = exp(s - 12), lane-partial denominators in registers.

#define KOFF 0
#define VOFF 16384
#define POFF 32768

__global__ __launch_bounds__(256) void flash_attn_kernel(
    const _Float16* __restrict__ q, const _Float16* __restrict__ k,
    const _Float16* __restrict__ vT, _Float16* __restrict__ attnb) {
  __shared__ __align__(16) _Float16 smem[40960];  // 80 KB
  const int t = threadIdx.x, wave = t >> 6, lane = t & 63, quad = lane >> 4, l16 = lane & 15;
  const int qt = blockIdx.x, bh = blockIdx.y, b = bh / NHEADS, h = bh % NHEADS;
  const _Float16* qbase = q + ((size_t)bh * SEQ + qt * 128) * HDIM;
  const _Float16* kbase = k + (size_t)bh * SEQ * HDIM;
  const _Float16* vbase = vT + (size_t)bh * HDIM * SEQ;
  const int wm = wave * 32;

  // stage Q 128x128 (16-granule swizzle) through [0,32KB), pull frags to regs
#pragma unroll
  for (int j = 0; j < 8; ++j) {
    int row = j * 16 + (t >> 4);
    int c = (t & 15) ^ (row & 15);
    __builtin_amdgcn_global_load_lds(GP(qbase + (size_t)row * HDIM + c * 8),
                                     LP(smem + j * 2048 + wave * 512), 16, 0, 0);
  }
  __syncthreads();  // full drain: Q visible to all waves
  h8 qf[2][4];
#pragma unroll
  for (int mt = 0; mt < 2; ++mt)
#pragma unroll
    for (int ks = 0; ks < 4; ++ks) {
      int row = wm + mt * 16 + l16;
      qf[mt][ks] = *reinterpret_cast<const h8*>(
          smem + row * 128 + ((ks * 4 + quad) ^ (row & 15)) * 8);
    }
  __syncthreads();  // all waves own their Q frags before K staging overwrites

  f32x4 oacc[2][8] = {};
  float lst[2][4] = {};  // lane-partial softmax denominators

  auto stageKV = [&](int tile, int bufi) {
    const int kt = tile * 64;
    _Float16* kb_ = smem + KOFF + bufi * 8192;
    _Float16* vb_ = smem + VOFF + bufi * 8192;
    // K tile: 64 keys x 128 d (16-granule swizzle)
#pragma unroll
    for (int j = 0; j < 4; ++j) {
      int row = j * 16 + (t >> 4);
      int c = (t & 15) ^ (row & 15);
      __builtin_amdgcn_global_load_lds(GP(kbase + (size_t)(kt + row) * HDIM + c * 8),
                                       LP(kb_ + j * 2048 + wave * 512), 16, 0, 0);
    }
    // V^T tile: 128 d x 64 s (8-granule swizzle)
#pragma unroll
    for (int j = 0; j < 4; ++j) {
      int row = j * 32 + (t >> 3);
      int c = (t & 7) ^ (row & 7);
      __builtin_amdgcn_global_load_lds(GP(vbase + (size_t)row * SEQ + kt + c * 8),
                                       LP(vb_ + j * 2048 + wave * 512), 16, 0, 0);
    }
  };

  // prologue: tiles 0,1 in flight (16 loads/thread)
  stageKV(0, 0);
  stageKV(1, 1);

  for (int tt = 0; tt < SEQ / 64; ++tt) {
    // own tile-tt loads landed (tile tt+1's 8 may remain), then barrier:
    // every wave pre-waited its own slice -> whole tile visible after barrier.
    asm volatile("s_waitcnt vmcnt(8)\n\ts_barrier" ::: "memory");

    const _Float16* kls = smem + KOFF + (tt & 1) * 8192;
    const _Float16* vls = smem + VOFF + (tt & 1) * 8192;

    // S = Q K^T (1/sqrt(d) pre-folded into q)
    f32x4 sacc[2][4] = {};
#pragma unroll
    for (int ks = 0; ks < 4; ++ks)
#pragma unroll
      for (int nt = 0; nt < 4; ++nt) {
        int rowB = nt * 16 + l16;
        h8 kf = *reinterpret_cast<const h8*>(
            kls + rowB * 128 + ((ks * 4 + quad) ^ (rowB & 15)) * 8);
#pragma unroll
        for (int mt = 0; mt < 2; ++mt)
          sacc[mt][nt] = __builtin_amdgcn_mfma_f32_16x16x32_f16(qf[mt][ks], kf, sacc[mt][nt], 0, 0, 0);
      }

    // p = exp(s - 12): write P to wave-exclusive LDS rows, accumulate
    // lane-partial denominators. No shuffles, no rescale, no barrier.
#pragma unroll
    for (int mt = 0; mt < 2; ++mt)
#pragma unroll
      for (int nt = 0; nt < 4; ++nt) {
        int colg = nt * 2 + (l16 >> 3);
        int ce = l16 & 7;
#pragma unroll
        for (int r = 0; r < 4; ++r) {
          float e = __expf(sacc[mt][nt][r] - 12.0f);
          lst[mt][r] += e;
          int row = wm + mt * 16 + quad * 4 + r;
          smem[POFF + row * 64 + ((colg ^ (row & 7)) * 8) + ce] = (_Float16)e;
        }
      }

    // O += P V  (P rows are wave-exclusive; intra-wave lgkmcnt orders it)
#pragma unroll
    for (int ks = 0; ks < 2; ++ks) {
      h8 pf[2];
#pragma unroll
      for (int mt = 0; mt < 2; ++mt) {
        int row = wm + mt * 16 + l16;
        pf[mt] = *reinterpret_cast<const h8*>(
            smem + POFF + row * 64 + ((ks * 4 + quad) ^ (row & 7)) * 8);
      }
#pragma unroll
      for (int nt = 0; nt < 8; ++nt) {
        int rowV = nt * 16 + l16;
        h8 vf = *reinterpret_cast<const h8*>(
            vls + rowV * 64 + ((ks * 4 + quad) ^ (rowV & 7)) * 8);
#pragma unroll
        for (int mt = 0; mt < 2; ++mt)
          oacc[mt][nt] = __builtin_amdgcn_mfma_f32_16x16x32_f16(pf[mt], vf, oacc[mt][nt], 0, 0, 0);
      }
    }

    // all waves done reading K/V[tt&1] -> safe to overwrite with tile tt+2.
    // No drain: tile tt+1's loads stay in flight across this barrier.
    asm volatile("s_barrier" ::: "memory");
    int dt = tt + 2;
    if (dt >= SEQ / 64) dt = SEQ / 64 - 1;  // clamp keeps vmcnt uniform
    stageKV(dt, tt & 1);
  }
  asm volatile("s_waitcnt vmcnt(0)" ::: "memory");  // drain tail stages

  // epilogue: reduce lane-partial denominators across l16, normalize, write
#pragma unroll
  for (int mt = 0; mt < 2; ++mt)
#pragma unroll
    for (int r = 0; r < 4; ++r) {
      float s = lst[mt][r];
#pragma unroll
      for (int off = 1; off <= 8; off <<= 1) s += __shfl_xor(s, off, 64);
      float inv = 1.f / s;
      int srow = qt * 128 + wm + mt * 16 + quad * 4 + r;
#pragma unroll
      for (int nt = 0; nt < 8; ++nt) {
        int d = nt * 16 + l16;
        attnb[((size_t)(b * SEQ + srow)) * DIM + h * HDIM + d] = (_Float16)(oacc[mt][nt][r] * inv);
      }
    }
}

// ---------------- launch ----------------

extern "C" void kernel_launch(void* const* d_in, const int* in_sizes, int n_in,
                              void* d_out, int out_size, void* d_ws, size_t ws_size,
                              hipStream_t stream) {
  const float* x  = (const float*)d_in[0];
  const float* Wq = (const float*)d_in[1];
  const float* bq = (const float*)d_in[2];
  const float* Wk = (const float*)d_in[3];
  const float* bk = (const float*)d_in[4];
  const float* Wv = (const float*)d_in[5];
  const float* bv = (const float*)d_in[6];
  const float* Wo = (const float*)d_in[7];
  const float* bo = (const float*)d_in[8];
  const float* gq = (const float*)d_in[9];
  const float* gk = (const float*)d_in[10];
  float* out = (float*)d_out;

  // workspace layout (total 186,777,600 B = 178.1 MiB)
  char* ws = (char*)d_ws;
  _Float16* xb    = (_Float16*)(ws);                 //  31,457,280 B
  _Float16* WT    = (_Float16*)(ws +  31457280LL);   //  29,491,200 B (reused x4)
  _Float16* qb    = (_Float16*)(ws +  60948480LL);   //  31,457,280 B
  _Float16* kb    = (_Float16*)(ws +  92405760LL);   //  31,457,280 B
  _Float16* vT    = (_Float16*)(ws + 123863040LL);   //  31,457,280 B
  _Float16* pre16 = (_Float16*)(ws + 155320320LL);   //  31,457,280 B
  _Float16* attnb = pre16;  // pre16 dead before flash writes attnb

  convert_h_kernel<<<15360, 256, 0, stream>>>(x, xb, MROWS * DIM);
  dim3 tgrid(DIM / 32, DIM / 32);
  const int ggrid = (DIM / 256) * (MROWS / 256);  // 15 * 16 = 240 blocks

  // Q
  transpose_convert_kernel<<<tgrid, 256, 0, stream>>>(Wq, WT, DIM, DIM);
  gemm_bt_kernel<_Float16><<<ggrid, 512, 0, stream>>>(xb, WT, bq, pre16, MROWS, DIM, DIM);
  rmsnorm_qk_kernel<<<MROWS, 256, 0, stream>>>(pre16, gq, qb, 0.08838834764831845f);  // 1/sqrt(128)
  // K
  transpose_convert_kernel<<<tgrid, 256, 0, stream>>>(Wk, WT, DIM, DIM);
  gemm_bt_kernel<_Float16><<<ggrid, 512, 0, stream>>>(xb, WT, bk, pre16, MROWS, DIM, DIM);
  rmsnorm_qk_kernel<<<MROWS, 256, 0, stream>>>(pre16, gk, kb, 1.0f);
  // V
  transpose_convert_kernel<<<tgrid, 256, 0, stream>>>(Wv, WT, DIM, DIM);
  gemm_bt_kernel<_Float16><<<ggrid, 512, 0, stream>>>(xb, WT, bv, pre16, MROWS, DIM, DIM);
  dim3 vgrid(SEQ / 32, HDIM / 32, BATCH * NHEADS);
  transpose_v_kernel<<<vgrid, 256, 0, stream>>>(pre16, vT);

  // attention
  dim3 agrid(SEQ / 128, BATCH * NHEADS);  // (16, 60)
  flash_attn_kernel<<<agrid, 256, 0, stream>>>(qb, kb, vT, attnb);

  // output projection
  transpose_convert_kernel<<<tgrid, 256, 0, stream>>>(Wo, WT, DIM, DIM);
  gemm_bt_kernel<float><<<ggrid, 512, 0, stream>>>(attnb, WT, bo, out, MROWS, DIM, DIM);
}